// Round 2
// baseline (169.228 us; speedup 1.0000x reference)
//
#include <hip/hip_runtime.h>

#define NB 2
#define NN 1024
#define NK 64
#define NG 64
#define NF 128
#define NH 4
#define NO 128
#define PITCH 132   // ys pitch in k_proj (bank-spread)

typedef unsigned short ushort_t;

__device__ __forceinline__ float bf2f(ushort_t u) {
    union { unsigned int i; float f; } v; v.i = ((unsigned int)u) << 16; return v.f;
}
__device__ __forceinline__ ushort_t f2bf(float f) {
    unsigned int u = __float_as_uint(f);
    unsigned int r = 0x7fffu + ((u >> 16) & 1u);
    return (ushort_t)((u + r) >> 16);
}
// shifted softplus: softplus(x) - log(2), numerically stable
__device__ __forceinline__ float sspf(float x) {
    return fmaxf(x, 0.f) + log1pf(expf(-fabsf(x))) - 0.69314718055994531f;
}

// Kernel 1: for 8 consecutive (b,n) rows:
//   y[b,h,n,f] = sum_i x[b,n,i] * w_in2f[h,i,f]
//   a_c[b,h,n] = sum_f y * w_att[h,f]   a_n[b,h,n] = sum_f y * w_att[h,F+f]
__global__ __launch_bounds__(256) void k_proj(
    const float* __restrict__ x,       // [B][N][F]
    const float* __restrict__ w_in2f,  // [H][F][F]
    const float* __restrict__ w_att,   // [H][2F]
    float* __restrict__ y,             // [B][H][N][F]
    float* __restrict__ a_c,           // [B][H][N]
    float* __restrict__ a_n)           // [B][H][N]
{
    const int bn0 = blockIdx.x * 8;
    const int t = threadIdx.x;
    __shared__ float xs[8][NF];        // 4 KB
    __shared__ float ys[32][PITCH];    // ~16.9 KB

    // stage 8 x-rows (1024 floats) coalesced
    {
        const float4* src = (const float4*)(x + (size_t)bn0 * NF);
        float4* dst = (float4*)(&xs[0][0]);
        dst[t] = src[t];
    }
    __syncthreads();

    const int hp = t >> 7;         // 0..1 -> heads (hp, hp+2)
    const int f0 = t & 127;
    const int h0 = hp, h1 = hp + 2;
    const float* w0 = w_in2f + (size_t)h0 * NF * NF + f0;
    const float* w1 = w_in2f + (size_t)h1 * NF * NF + f0;
    float acc0[8], acc1[8];
    #pragma unroll
    for (int n = 0; n < 8; ++n) { acc0[n] = 0.f; acc1[n] = 0.f; }

    for (int i0 = 0; i0 < NF; i0 += 4) {
        float4 xv[8];
        #pragma unroll
        for (int n = 0; n < 8; ++n) xv[n] = *(const float4*)&xs[n][i0];
        #pragma unroll
        for (int ii = 0; ii < 4; ++ii) {
            const float wa = w0[(size_t)(i0 + ii) * NF];
            const float wb = w1[(size_t)(i0 + ii) * NF];
            #pragma unroll
            for (int n = 0; n < 8; ++n) {
                const float xi = (&xv[n].x)[ii];
                acc0[n] = fmaf(xi, wa, acc0[n]);
                acc1[n] = fmaf(xi, wb, acc1[n]);
            }
        }
    }
    #pragma unroll
    for (int n = 0; n < 8; ++n) {
        const int bn = bn0 + n;
        const int b = bn >> 10, nn = bn & (NN - 1);
        y[((size_t)(b * NH + h0) * NN + nn) * NF + f0] = acc0[n];
        y[((size_t)(b * NH + h1) * NN + nn) * NF + f0] = acc1[n];
        ys[n * 4 + h0][f0] = acc0[n];
        ys[n * 4 + h1][f0] = acc1[n];
    }
    __syncthreads();

    // attention dots: 32 (h,n) pairs x 8 lanes each
    {
        const int hn = t >> 3, q = t & 7;
        const int h = hn & 3, n = hn >> 2;
        float pc = 0.f, pn = 0.f;
        #pragma unroll
        for (int j = 0; j < 16; ++j) {
            const int f = q + 8 * j;
            const float yv = ys[n * 4 + h][f];
            pc = fmaf(yv, w_att[h * 2 * NF + f], pc);
            pn = fmaf(yv, w_att[h * 2 * NF + NF + f], pn);
        }
        #pragma unroll
        for (int off = 1; off < 8; off <<= 1) {
            pc += __shfl_xor(pc, off, 8);
            pn += __shfl_xor(pn, off, 8);
        }
        if (q == 0) {
            const int bn = bn0 + n;
            const int b = bn >> 10, nn = bn & (NN - 1);
            a_c[(size_t)(b * NH + h) * NN + nn] = pc;
            a_n[(size_t)(b * NH + h) * NN + nn] = pn;
        }
    }
}

// Kernel 2: fused filter-net + attention + aggregate + output projection,
// one workgroup per (b,n). LDS ~67 KB -> 2 blocks/CU.
__global__ __launch_bounds__(256) void k_main(
    const int*   __restrict__ neighbors, // [B][N][K]
    const float* __restrict__ pmask,     // [B][N][K]
    const float* __restrict__ f_ij,      // [B][N][K][G]
    const float* __restrict__ wf1,       // [G][F]
    const float* __restrict__ bf1,       // [F]
    const float* __restrict__ wf2,       // [F][F]
    const float* __restrict__ bf2v,      // [F]
    const float* __restrict__ w_out,     // [F][O]
    const float* __restrict__ b_out,     // [O]
    const float* __restrict__ y,         // [B][H][N][F]
    const float* __restrict__ a_c,       // [B][H][N]
    const float* __restrict__ a_n,       // [B][H][N]
    float*       __restrict__ outp)      // [B][N][O]
{
    const int bn = blockIdx.x;
    const int b = bn >> 10, n_ = bn & (NN - 1);
    const int t = threadIdx.x;

    __shared__ float    fij_s[NK][NG];   // 16 KB, row-major [k][g]
    __shared__ float    W1sT[NF][NK];    // 32 KB, transposed, 16B-chunk XOR swizzled
    __shared__ ushort_t W2s[NK][NF];     // 16 KB bf16
    __shared__ float    alpha_s[NH][NK]; // 1 KB (mask folded in)
    __shared__ int      nbs[NK];
    __shared__ float    aggp[2][NF];
    __shared__ float    aggc[NF];

    // stage f_ij tile (4096 f32 = 16 KB) coalesced
    {
        const float4* src = (const float4*)(f_ij + (size_t)bn * NK * NG);
        float4* dst = (float4*)(&fij_s[0][0]);
        #pragma unroll
        for (int it = 0; it < 4; ++it) dst[it * 256 + t] = src[it * 256 + t];
    }
    if (t < NK) nbs[t] = neighbors[(size_t)bn * NK + t];
    __syncthreads();

    const int kt = t >> 5;   // 0..7 -> k block of 8
    const int ft = t & 31;   // 0..31 -> f block of 4

    // Phase A1: W1 = ssp(f_ij @ wf1 + bf1), stored transposed+swizzled in W1sT
    {
        float acc[8][4];
        #pragma unroll
        for (int j = 0; j < 8; ++j)
            #pragma unroll
            for (int c = 0; c < 4; ++c) acc[j][c] = 0.f;

        for (int gs = 0; gs < 8; ++gs) {
            float fv[8][8];
            #pragma unroll
            for (int j = 0; j < 8; ++j) {
                const float4 p0 = *(const float4*)&fij_s[kt * 8 + j][gs * 8];
                const float4 p1 = *(const float4*)&fij_s[kt * 8 + j][gs * 8 + 4];
                fv[j][0] = p0.x; fv[j][1] = p0.y; fv[j][2] = p0.z; fv[j][3] = p0.w;
                fv[j][4] = p1.x; fv[j][5] = p1.y; fv[j][6] = p1.z; fv[j][7] = p1.w;
            }
            #pragma unroll
            for (int gg = 0; gg < 8; ++gg) {
                const float4 w = *(const float4*)&wf1[(size_t)(gs * 8 + gg) * NF + ft * 4];
                #pragma unroll
                for (int j = 0; j < 8; ++j) {
                    acc[j][0] = fmaf(fv[j][gg], w.x, acc[j][0]);
                    acc[j][1] = fmaf(fv[j][gg], w.y, acc[j][1]);
                    acc[j][2] = fmaf(fv[j][gg], w.z, acc[j][2]);
                    acc[j][3] = fmaf(fv[j][gg], w.w, acc[j][3]);
                }
            }
        }
        const float4 bv = *(const float4*)&bf1[ft * 4];
        #pragma unroll
        for (int c = 0; c < 4; ++c) {
            const float bb = (&bv.x)[c];
            const int r = ft * 4 + c;
            const int srow = r & 15;
            float4 p0, p1;
            p0.x = sspf(acc[0][c] + bb); p0.y = sspf(acc[1][c] + bb);
            p0.z = sspf(acc[2][c] + bb); p0.w = sspf(acc[3][c] + bb);
            p1.x = sspf(acc[4][c] + bb); p1.y = sspf(acc[5][c] + bb);
            p1.z = sspf(acc[6][c] + bb); p1.w = sspf(acc[7][c] + bb);
            char* rowp = (char*)&W1sT[r][0];
            *(float4*)(rowp + (((kt * 2)     ^ srow) << 4)) = p0;
            *(float4*)(rowp + (((kt * 2 + 1) ^ srow) << 4)) = p1;
        }
    }
    __syncthreads();

    // Phase A2: W2 = W1 @ wf2 + bf2 -> bf16 in W2s
    {
        float acc[8][4];
        #pragma unroll
        for (int j = 0; j < 8; ++j)
            #pragma unroll
            for (int c = 0; c < 4; ++c) acc[j][c] = 0.f;

        for (int i = 0; i < NF; ++i) {
            const char* rowp = (const char*)&W1sT[i][0];
            const int si = i & 15;
            const float4 a0 = *(const float4*)(rowp + (((kt * 2)     ^ si) << 4));
            const float4 a1 = *(const float4*)(rowp + (((kt * 2 + 1) ^ si) << 4));
            float wv[8];
            wv[0] = a0.x; wv[1] = a0.y; wv[2] = a0.z; wv[3] = a0.w;
            wv[4] = a1.x; wv[5] = a1.y; wv[6] = a1.z; wv[7] = a1.w;
            const float4 w = *(const float4*)&wf2[(size_t)i * NF + ft * 4];
            #pragma unroll
            for (int j = 0; j < 8; ++j) {
                acc[j][0] = fmaf(wv[j], w.x, acc[j][0]);
                acc[j][1] = fmaf(wv[j], w.y, acc[j][1]);
                acc[j][2] = fmaf(wv[j], w.z, acc[j][2]);
                acc[j][3] = fmaf(wv[j], w.w, acc[j][3]);
            }
        }
        const float4 bv = *(const float4*)&bf2v[ft * 4];
        #pragma unroll
        for (int j = 0; j < 8; ++j) {
            union { ushort_t u[4]; uint2 v; } pk;
            pk.u[0] = f2bf(acc[j][0] + bv.x);
            pk.u[1] = f2bf(acc[j][1] + bv.y);
            pk.u[2] = f2bf(acc[j][2] + bv.z);
            pk.u[3] = f2bf(acc[j][3] + bv.w);
            *(uint2*)&W2s[kt * 8 + j][ft * 4] = pk.v;
        }
    }
    __syncthreads();

    // Phase B: att logits from precomputed a_c/a_n + per-head softmax (wave==head)
    {
        const int h = t >> 6, k = t & 63;
        const int nb = nbs[k];
        const float av = a_c[(size_t)(b * NH + h) * NN + n_]
                       + a_n[(size_t)(b * NH + h) * NN + nb];
        const float att = sspf(av);
        float m = att;
        #pragma unroll
        for (int off = 32; off > 0; off >>= 1) m = fmaxf(m, __shfl_xor(m, off, 64));
        const float e = expf(att - m);
        float s = e;
        #pragma unroll
        for (int off = 32; off > 0; off >>= 1) s += __shfl_xor(s, off, 64);
        alpha_s[h][k] = (e / s) * pmask[(size_t)bn * NK + k];
    }
    __syncthreads();

    // Phase C: agg[f] = (1/H) * sum_k W2[k][f] * sum_h alpha'[h][k]*y[b,h,nb_k,f]
    {
        const int f = t & 127, kg = t >> 7;
        const float* ybf = y + (size_t)b * NH * NN * NF + f;
        float acc = 0.f;
        for (int kk = 0; kk < 32; ++kk) {
            const int k = kg * 32 + kk;
            const int nb = nbs[k];
            const float* yp = ybf + (size_t)nb * NF;
            float s = alpha_s[0][k] * yp[0]
                    + alpha_s[1][k] * yp[(size_t)NN * NF]
                    + alpha_s[2][k] * yp[2 * (size_t)NN * NF]
                    + alpha_s[3][k] * yp[3 * (size_t)NN * NF];
            acc = fmaf(bf2f(W2s[k][f]), s, acc);
        }
        aggp[kg][f] = acc;
    }
    __syncthreads();
    if (t < NF) aggc[t] = (aggp[0][t] + aggp[1][t]) * 0.25f;  // /H
    __syncthreads();

    // Phase D: out = ssp(agg @ w_out + b_out)
    if (t < NO) {
        float z = b_out[t];
        #pragma unroll 4
        for (int f = 0; f < NF; ++f)
            z = fmaf(aggc[f], w_out[(size_t)f * NO + t], z);
        outp[(size_t)bn * NO + t] = sspf(z);
    }
}

extern "C" void kernel_launch(void* const* d_in, const int* in_sizes, int n_in,
                              void* d_out, int out_size, void* d_ws, size_t ws_size,
                              hipStream_t stream) {
    const float* x      = (const float*)d_in[0];
    // d_in[1] = r_ij (unused by reference)
    const int*   nbr    = (const int*)d_in[2];
    const float* pmask  = (const float*)d_in[3];
    const float* f_ij   = (const float*)d_in[4];
    const float* w_in2f = (const float*)d_in[5];
    const float* w_att  = (const float*)d_in[6];
    const float* wf1    = (const float*)d_in[7];
    const float* bf1    = (const float*)d_in[8];
    const float* wf2    = (const float*)d_in[9];
    const float* bf2v   = (const float*)d_in[10];
    const float* w_out  = (const float*)d_in[11];
    const float* b_out  = (const float*)d_in[12];

    float* y   = (float*)d_ws;                        // B*H*N*F f32 = 4 MB
    float* a_c = y + (size_t)NB * NH * NN * NF;       // B*H*N
    float* a_n = a_c + (size_t)NB * NH * NN;          // B*H*N

    float* outp = (float*)d_out;

    k_proj<<<NB * NN / 8, 256, 0, stream>>>(x, w_in2f, w_att, y, a_c, a_n);
    k_main<<<NB * NN, 256, 0, stream>>>(nbr, pmask, f_ij, wf1, bf1, wf2, bf2v,
                                        w_out, b_out, y, a_c, a_n, outp);
}

// Round 5
// 100.784 us; speedup vs baseline: 1.6791x; 1.6791x over previous
//
#include <hip/hip_runtime.h>

#define NB 2
#define NN 1024
#define NK 64
#define NG 64
#define NF 128
#define NH 4
#define NO 128
#define PITCH 132   // ys pitch in k_proj (bank-spread)

typedef unsigned short ushort_t;
typedef __attribute__((ext_vector_type(8))) short short8v;
typedef __attribute__((ext_vector_type(4))) float f32x4;

union FragU { uint4 u4; short8v s8; };

__device__ __forceinline__ float bf2f(ushort_t u) {
    union { unsigned int i; float f; } v; v.i = ((unsigned int)u) << 16; return v.f;
}
__device__ __forceinline__ ushort_t f2bf(float f) {
    unsigned int u = __float_as_uint(f);
    unsigned int r = 0x7fffu + ((u >> 16) & 1u);
    return (ushort_t)((u + r) >> 16);
}
// shifted softplus: softplus(x) - log(2), numerically stable
__device__ __forceinline__ float sspf(float x) {
    return fmaxf(x, 0.f) + log1pf(expf(-fabsf(x))) - 0.69314718055994531f;
}

// ---------------------------------------------------------------------------
// Prep: split wf1/wf2 into bf16 hi/lo B-fragment tables (fragment-linear).
// table[(fi*64 + lane)*8 + j], fi = ks*8 + nf; element j maps to
// k = ks*32 + ((lane>>4)&3)*4 + (j&3) + 16*(j>>2), n = nf*16 + (lane&15).
// wf1f: 16 fi -> 1024 lane-slots hi + 1024 lo (elem offset 8192)
// wf2f: 32 fi -> 2048 lane-slots hi + 2048 lo (elem offset 16384)
// ---------------------------------------------------------------------------
__global__ __launch_bounds__(256) void k_prep(
    const float* __restrict__ wf1, const float* __restrict__ wf2,
    ushort_t* __restrict__ wf1f, ushort_t* __restrict__ wf2f)
{
    int s = blockIdx.x * 256 + threadIdx.x;
    if (s >= 3072) return;
    const float* W; ushort_t* out; int loOff;
    if (s < 1024) { W = wf1; out = wf1f; loOff = 8192; }
    else          { s -= 1024; W = wf2; out = wf2f; loOff = 16384; }
    const int fi = s >> 6, lane = s & 63;
    const int ks = fi >> 3, nf = fi & 7;
    const int n = nf * 16 + (lane & 15);
    const int kb = ks * 32 + ((lane >> 4) & 3) * 4;
    #pragma unroll
    for (int j = 0; j < 8; ++j) {
        const int k = kb + (j & 3) + ((j >> 2) << 4);
        const float v = W[(size_t)k * NF + n];
        const ushort_t hb = f2bf(v);
        out[(size_t)(fi * 64 + lane) * 8 + j] = hb;
        out[(size_t)loOff + (fi * 64 + lane) * 8 + j] = f2bf(v - bf2f(hb));
    }
}

// ---------------------------------------------------------------------------
// Kernel 1: y (bf16) + attention dots a_c / a_n (fp32, computed pre-rounding)
// ---------------------------------------------------------------------------
__global__ __launch_bounds__(256) void k_proj(
    const float* __restrict__ x,       // [B][N][F]
    const float* __restrict__ w_in2f,  // [H][F][F]
    const float* __restrict__ w_att,   // [H][2F]
    ushort_t* __restrict__ y,          // [B][H][N][F] bf16
    float* __restrict__ a_c,           // [B][H][N]
    float* __restrict__ a_n)           // [B][H][N]
{
    const int bn0 = blockIdx.x * 8;
    const int t = threadIdx.x;
    __shared__ float xs[8][NF];
    __shared__ float ys[32][PITCH];

    {
        const float4* src = (const float4*)(x + (size_t)bn0 * NF);
        float4* dst = (float4*)(&xs[0][0]);
        dst[t] = src[t];
    }
    __syncthreads();

    const int hp = t >> 7;
    const int f0 = t & 127;
    const int h0 = hp, h1 = hp + 2;
    const float* w0 = w_in2f + (size_t)h0 * NF * NF + f0;
    const float* w1 = w_in2f + (size_t)h1 * NF * NF + f0;
    float acc0[8], acc1[8];
    #pragma unroll
    for (int n = 0; n < 8; ++n) { acc0[n] = 0.f; acc1[n] = 0.f; }

    for (int i0 = 0; i0 < NF; i0 += 4) {
        float4 xv[8];
        #pragma unroll
        for (int n = 0; n < 8; ++n) xv[n] = *(const float4*)&xs[n][i0];
        #pragma unroll
        for (int ii = 0; ii < 4; ++ii) {
            const float wa = w0[(size_t)(i0 + ii) * NF];
            const float wb = w1[(size_t)(i0 + ii) * NF];
            #pragma unroll
            for (int n = 0; n < 8; ++n) {
                const float xi = (&xv[n].x)[ii];
                acc0[n] = fmaf(xi, wa, acc0[n]);
                acc1[n] = fmaf(xi, wb, acc1[n]);
            }
        }
    }
    #pragma unroll
    for (int n = 0; n < 8; ++n) {
        const int bn = bn0 + n;
        const int b = bn >> 10, nn = bn & (NN - 1);
        y[((size_t)(b * NH + h0) * NN + nn) * NF + f0] = f2bf(acc0[n]);
        y[((size_t)(b * NH + h1) * NN + nn) * NF + f0] = f2bf(acc1[n]);
        ys[n * 4 + h0][f0] = acc0[n];
        ys[n * 4 + h1][f0] = acc1[n];
    }
    __syncthreads();

    {
        const int hn = t >> 3, q = t & 7;
        const int h = hn & 3, n = hn >> 2;
        float pc = 0.f, pn = 0.f;
        #pragma unroll
        for (int j = 0; j < 16; ++j) {
            const int f = q + 8 * j;
            const float yv = ys[n * 4 + h][f];
            pc = fmaf(yv, w_att[h * 2 * NF + f], pc);
            pn = fmaf(yv, w_att[h * 2 * NF + NF + f], pn);
        }
        #pragma unroll
        for (int off = 1; off < 8; off <<= 1) {
            pc += __shfl_xor(pc, off, 8);
            pn += __shfl_xor(pn, off, 8);
        }
        if (q == 0) {
            const int bn = bn0 + n;
            const int b = bn >> 10, nn = bn & (NN - 1);
            a_c[(size_t)(b * NH + h) * NN + nn] = pc;
            a_n[(size_t)(b * NH + h) * NN + nn] = pn;
        }
    }
}

// ---------------------------------------------------------------------------
// Kernel 2: MFMA filter-net + attention + aggregate + out-proj, one wg/(b,n)
// LDS map (52480 B):
//   [0     ..33792)  W1h/W1l [64][132] ushort each  -> (after A2 barrier)
//                    W2f [64][132] f32 overlay
//   [33792 ..51200)  fijh/fijl [64][68] ushort      -> (after A1) aggp[8][128]
//                    f32 @33792 + aggc[128] f32 @37888
//   [51200 ..52224)  alpha [4][64] f32
//   [52224 ..52480)  nbs [64] int
// ---------------------------------------------------------------------------
__global__ __launch_bounds__(256, 3) void k_main(
    const int*      __restrict__ neighbors, // [B][N][K]
    const float*    __restrict__ pmask,     // [B][N][K]
    const float*    __restrict__ f_ij,      // [B][N][K][G]
    const float*    __restrict__ bf1,       // [F]
    const float*    __restrict__ bf2v,      // [F]
    const float*    __restrict__ w_out,     // [F][O]
    const float*    __restrict__ b_out,     // [O]
    const ushort_t* __restrict__ y,         // [B][H][N][F] bf16
    const float*    __restrict__ a_c,       // [B][H][N]
    const float*    __restrict__ a_n,       // [B][H][N]
    const ushort_t* __restrict__ wf1f,      // frag table hi/lo
    const ushort_t* __restrict__ wf2f,      // frag table hi/lo
    float*          __restrict__ outp)      // [B][N][O]
{
    const int bn = blockIdx.x;
    const int b = bn >> 10, n_ = bn & (NN - 1);
    const int t = threadIdx.x;

    __shared__ __align__(16) char smem[52480];
    ushort_t* W1h  = (ushort_t*)(smem);
    ushort_t* W1l  = (ushort_t*)(smem + 16896);
    ushort_t* fijh = (ushort_t*)(smem + 33792);
    ushort_t* fijl = (ushort_t*)(smem + 42496);
    float*    W2f  = (float*)(smem);              // overlay after A2 barrier
    float*    alpha = (float*)(smem + 51200);
    int*      nbs   = (int*)(smem + 52224);
    float*    aggp  = (float*)(smem + 33792);     // overlay fij (dead after A1)
    float*    aggc  = (float*)(smem + 37888);

    const int wave = t >> 6, lane = t & 63;
    const int lrow = lane & 15;          // A-row / B-col / C-col within frag
    const int lq   = (lane >> 4) & 3;    // quarter
    const int wb   = wave * 32;          // this wave's N-column base

    // ---- stage f_ij (fp32 global, coalesced) -> bf16 hi/lo LDS ----
    {
        const float4* src = (const float4*)(f_ij + (size_t)bn * NK * NG);
        #pragma unroll
        for (int i = 0; i < 4; ++i) {
            const int e4 = i * 256 + t;
            const float4 v = src[e4];
            const int e = e4 * 4;
            const int row = e >> 6, col = e & 63;
            const ushort_t h0 = f2bf(v.x), h1 = f2bf(v.y), h2 = f2bf(v.z), h3 = f2bf(v.w);
            uint2 ph, pl;
            ph.x = (unsigned)h0 | ((unsigned)h1 << 16);
            ph.y = (unsigned)h2 | ((unsigned)h3 << 16);
            pl.x = (unsigned)f2bf(v.x - bf2f(h0)) | ((unsigned)f2bf(v.y - bf2f(h1)) << 16);
            pl.y = (unsigned)f2bf(v.z - bf2f(h2)) | ((unsigned)f2bf(v.w - bf2f(h3)) << 16);
            *(uint2*)&fijh[row * 68 + col] = ph;
            *(uint2*)&fijl[row * 68 + col] = pl;
        }
    }
    if (t < NK) nbs[t] = neighbors[(size_t)bn * NK + t];
    __syncthreads();

    // ---- Phase A1: W1 = ssp(f_ij @ wf1 + bf1), 4-term bf16x2-split MFMA ----
    {
        FragU b1h[2][2], b1l[2][2];
        #pragma unroll
        for (int ks = 0; ks < 2; ++ks)
            #pragma unroll
            for (int nf2 = 0; nf2 < 2; ++nf2) {
                const int fi = ks * 8 + wave * 2 + nf2;
                b1h[ks][nf2].u4 = *((const uint4*)wf1f + fi * 64 + lane);
                b1l[ks][nf2].u4 = *((const uint4*)(wf1f + 8192) + fi * 64 + lane);
            }
        f32x4 acc[4][2];
        #pragma unroll
        for (int mf = 0; mf < 4; ++mf)
            #pragma unroll
            for (int nf2 = 0; nf2 < 2; ++nf2) acc[mf][nf2] = (f32x4)0.f;

        #pragma unroll
        for (int mf = 0; mf < 4; ++mf) {
            const int row = mf * 16 + lrow;
            #pragma unroll
            for (int ks = 0; ks < 2; ++ks) {
                const int cb = ks * 32 + lq * 4;
                FragU ah, al;
                {
                    const uint2 p0 = *(const uint2*)&fijh[row * 68 + cb];
                    const uint2 p1 = *(const uint2*)&fijh[row * 68 + cb + 16];
                    uint4 q; q.x = p0.x; q.y = p0.y; q.z = p1.x; q.w = p1.y; ah.u4 = q;
                }
                {
                    const uint2 p0 = *(const uint2*)&fijl[row * 68 + cb];
                    const uint2 p1 = *(const uint2*)&fijl[row * 68 + cb + 16];
                    uint4 q; q.x = p0.x; q.y = p0.y; q.z = p1.x; q.w = p1.y; al.u4 = q;
                }
                #pragma unroll
                for (int nf2 = 0; nf2 < 2; ++nf2) {
                    acc[mf][nf2] = __builtin_amdgcn_mfma_f32_16x16x32_bf16(ah.s8, b1h[ks][nf2].s8, acc[mf][nf2], 0, 0, 0);
                    acc[mf][nf2] = __builtin_amdgcn_mfma_f32_16x16x32_bf16(ah.s8, b1l[ks][nf2].s8, acc[mf][nf2], 0, 0, 0);
                    acc[mf][nf2] = __builtin_amdgcn_mfma_f32_16x16x32_bf16(al.s8, b1h[ks][nf2].s8, acc[mf][nf2], 0, 0, 0);
                    acc[mf][nf2] = __builtin_amdgcn_mfma_f32_16x16x32_bf16(al.s8, b1l[ks][nf2].s8, acc[mf][nf2], 0, 0, 0);
                }
            }
        }
        const float bia[2] = { bf1[wb + lrow], bf1[wb + 16 + lrow] };
        #pragma unroll
        for (int mf = 0; mf < 4; ++mf)
            #pragma unroll
            for (int nf2 = 0; nf2 < 2; ++nf2) {
                const int col = wb + nf2 * 16 + lrow;
                #pragma unroll
                for (int r = 0; r < 4; ++r) {
                    const int row = mf * 16 + lq * 4 + r;
                    const float w = sspf(acc[mf][nf2][r] + bia[nf2]);
                    const ushort_t hb = f2bf(w);
                    W1h[row * 132 + col] = hb;
                    W1l[row * 132 + col] = f2bf(w - bf2f(hb));
                }
            }
    }
    __syncthreads();

    // ---- Phase A2: W2 = W1 @ wf2 + bf2, 4-term split MFMA; W2 kept fp32 ----
    {
        f32x4 acc[4][2];
        #pragma unroll
        for (int mf = 0; mf < 4; ++mf)
            #pragma unroll
            for (int nf2 = 0; nf2 < 2; ++nf2) acc[mf][nf2] = (f32x4)0.f;

        for (int ks = 0; ks < 4; ++ks) {
            FragU b2h[2], b2l[2];
            #pragma unroll
            for (int nf2 = 0; nf2 < 2; ++nf2) {
                const int fi = ks * 8 + wave * 2 + nf2;
                b2h[nf2].u4 = *((const uint4*)wf2f + fi * 64 + lane);
                b2l[nf2].u4 = *((const uint4*)(wf2f + 16384) + fi * 64 + lane);
            }
            const int cb = ks * 32 + lq * 4;
            #pragma unroll
            for (int mf = 0; mf < 4; ++mf) {
                const int row = mf * 16 + lrow;
                FragU ah, al;
                {
                    const uint2 p0 = *(const uint2*)&W1h[row * 132 + cb];
                    const uint2 p1 = *(const uint2*)&W1h[row * 132 + cb + 16];
                    uint4 q; q.x = p0.x; q.y = p0.y; q.z = p1.x; q.w = p1.y; ah.u4 = q;
                }
                {
                    const uint2 p0 = *(const uint2*)&W1l[row * 132 + cb];
                    const uint2 p1 = *(const uint2*)&W1l[row * 132 + cb + 16];
                    uint4 q; q.x = p0.x; q.y = p0.y; q.z = p1.x; q.w = p1.y; al.u4 = q;
                }
                #pragma unroll
                for (int nf2 = 0; nf2 < 2; ++nf2) {
                    acc[mf][nf2] = __builtin_amdgcn_mfma_f32_16x16x32_bf16(ah.s8, b2h[nf2].s8, acc[mf][nf2], 0, 0, 0);
                    acc[mf][nf2] = __builtin_amdgcn_mfma_f32_16x16x32_bf16(ah.s8, b2l[nf2].s8, acc[mf][nf2], 0, 0, 0);
                    acc[mf][nf2] = __builtin_amdgcn_mfma_f32_16x16x32_bf16(al.s8, b2h[nf2].s8, acc[mf][nf2], 0, 0, 0);
                    acc[mf][nf2] = __builtin_amdgcn_mfma_f32_16x16x32_bf16(al.s8, b2l[nf2].s8, acc[mf][nf2], 0, 0, 0);
                }
            }
        }
        __syncthreads();   // all W1 reads done before W2f overlays the region
        const float bia[2] = { bf2v[wb + lrow], bf2v[wb + 16 + lrow] };
        #pragma unroll
        for (int mf = 0; mf < 4; ++mf)
            #pragma unroll
            for (int nf2 = 0; nf2 < 2; ++nf2) {
                const int col = wb + nf2 * 16 + lrow;
                #pragma unroll
                for (int r = 0; r < 4; ++r) {
                    const int row = mf * 16 + lq * 4 + r;
                    W2f[row * 132 + col] = acc[mf][nf2][r] + bia[nf2];
                }
            }
    }

    // ---- Phase B: attention softmax (wave == head), mask folded into alpha ----
    {
        const int h = wave, k = lane;
        const int nb = nbs[k];
        const float av = a_c[(size_t)(b * NH + h) * NN + n_]
                       + a_n[(size_t)(b * NH + h) * NN + nb];
        const float att = sspf(av);
        float m = att;
        #pragma unroll
        for (int off = 32; off > 0; off >>= 1) m = fmaxf(m, __shfl_xor(m, off, 64));
        const float e = expf(att - m);
        float s = e;
        #pragma unroll
        for (int off = 32; off > 0; off >>= 1) s += __shfl_xor(s, off, 64);
        alpha[h * 64 + k] = (e / s) * pmask[(size_t)bn * NK + k];
    }
    __syncthreads();   // orders W2f + alpha writes before Phase C reads

    // ---- Phase C: agg[f] = (1/H) sum_k W2[k][f] * sum_h alpha[h][k]*y[b,h,nb,f] ----
    {
        const int fq = (t & 31) * 4;
        const int kg = t >> 5;          // 0..7
        float4 accv; accv.x = accv.y = accv.z = accv.w = 0.f;
        const ushort_t* yb = y + (size_t)b * NH * NN * NF;
        #pragma unroll 2
        for (int kk = 0; kk < 8; ++kk) {
            const int k = kg * 8 + kk;
            const int nb = nbs[k];
            const ushort_t* yp = yb + (size_t)nb * NF + fq;
            const uint2 u0 = *(const uint2*)(yp);
            const uint2 u1 = *(const uint2*)(yp + (size_t)NN * NF);
            const uint2 u2 = *(const uint2*)(yp + 2 * (size_t)NN * NF);
            const uint2 u3 = *(const uint2*)(yp + 3 * (size_t)NN * NF);
            const float a0 = alpha[0 * 64 + k], a1 = alpha[1 * 64 + k];
            const float a2 = alpha[2 * 64 + k], a3 = alpha[3 * 64 + k];
            float4 s;
            s.x = fmaf(a3, bf2f((ushort_t)(u3.x & 0xffffu)),
                  fmaf(a2, bf2f((ushort_t)(u2.x & 0xffffu)),
                  fmaf(a1, bf2f((ushort_t)(u1.x & 0xffffu)),
                       a0 * bf2f((ushort_t)(u0.x & 0xffffu)))));
            s.y = fmaf(a3, bf2f((ushort_t)(u3.x >> 16)),
                  fmaf(a2, bf2f((ushort_t)(u2.x >> 16)),
                  fmaf(a1, bf2f((ushort_t)(u1.x >> 16)),
                       a0 * bf2f((ushort_t)(u0.x >> 16)))));
            s.z = fmaf(a3, bf2f((ushort_t)(u3.y & 0xffffu)),
                  fmaf(a2, bf2f((ushort_t)(u2.y & 0xffffu)),
                  fmaf(a1, bf2f((ushort_t)(u1.y & 0xffffu)),
                       a0 * bf2f((ushort_t)(u0.y & 0xffffu)))));
            s.w = fmaf(a3, bf2f((ushort_t)(u3.y >> 16)),
                  fmaf(a2, bf2f((ushort_t)(u2.y >> 16)),
                  fmaf(a1, bf2f((ushort_t)(u1.y >> 16)),
                       a0 * bf2f((ushort_t)(u0.y >> 16)))));
            const float4 wv = *(const float4*)&W2f[k * 132 + fq];
            accv.x = fmaf(wv.x, s.x, accv.x);
            accv.y = fmaf(wv.y, s.y, accv.y);
            accv.z = fmaf(wv.z, s.z, accv.z);
            accv.w = fmaf(wv.w, s.w, accv.w);
        }
        *(float4*)&aggp[kg * 128 + fq] = accv;
    }
    __syncthreads();
    if (t < NF) {
        float s = 0.f;
        #pragma unroll
        for (int q = 0; q < 8; ++q) s += aggp[q * 128 + t];
        aggc[t] = s * 0.25f;   // / H
    }
    __syncthreads();

    // ---- Phase D: out = ssp(agg @ w_out + b_out) ----
    if (t < NO) {
        float z = b_out[t];
        #pragma unroll 4
        for (int f = 0; f < NF; ++f)
            z = fmaf(aggc[f], w_out[(size_t)f * NO + t], z);
        outp[(size_t)bn * NO + t] = sspf(z);
    }
}

extern "C" void kernel_launch(void* const* d_in, const int* in_sizes, int n_in,
                              void* d_out, int out_size, void* d_ws, size_t ws_size,
                              hipStream_t stream) {
    const float* x      = (const float*)d_in[0];
    // d_in[1] = r_ij (unused by reference)
    const int*   nbr    = (const int*)d_in[2];
    const float* pmask  = (const float*)d_in[3];
    const float* f_ij   = (const float*)d_in[4];
    const float* w_in2f = (const float*)d_in[5];
    const float* w_att  = (const float*)d_in[6];
    const float* wf1    = (const float*)d_in[7];
    const float* bf1    = (const float*)d_in[8];
    const float* wf2    = (const float*)d_in[9];
    const float* bf2v   = (const float*)d_in[10];
    const float* w_out  = (const float*)d_in[11];
    const float* b_out  = (const float*)d_in[12];

    // ws layout (total 2.16 MB, well inside proven-writable bounds):
    //   yb16  [B][H][N][F] bf16 : 2 MB
    //   a_c   [B][H][N] f32     : 32 KB
    //   a_n   [B][H][N] f32     : 32 KB
    //   wf1f  hi+lo bf16 tables : 32 KB
    //   wf2f  hi+lo bf16 tables : 64 KB
    ushort_t* yb16 = (ushort_t*)d_ws;
    float*    a_c  = (float*)(yb16 + (size_t)NB * NH * NN * NF);
    float*    a_n  = a_c + (size_t)NB * NH * NN;
    ushort_t* wf1f = (ushort_t*)(a_n + (size_t)NB * NH * NN);
    ushort_t* wf2f = wf1f + 16384;

    float* outp = (float*)d_out;

    k_prep<<<12, 256, 0, stream>>>(wf1, wf2, wf1f, wf2f);
    k_proj<<<NB * NN / 8, 256, 0, stream>>>(x, w_in2f, w_att, yb16, a_c, a_n);
    k_main<<<NB * NN, 256, 0, stream>>>(nbr, pmask, f_ij, bf1, bf2v,
                                        w_out, b_out, yb16, a_c, a_n, wf1f, wf2f, outp);
}

// Round 6
// 91.785 us; speedup vs baseline: 1.8437x; 1.0980x over previous
//
#include <hip/hip_runtime.h>

#define NB 2
#define NN 1024
#define NK 64
#define NG 64
#define NF 128
#define NH 4
#define NO 128
#define PITCH 132   // ys pitch in k_proj (bank-spread)

typedef unsigned short ushort_t;
typedef __attribute__((ext_vector_type(8))) short short8v;
typedef __attribute__((ext_vector_type(4))) float f32x4;

union FragU { uint4 u4; short8v s8; };

__device__ __forceinline__ float bf2f(ushort_t u) {
    union { unsigned int i; float f; } v; v.i = ((unsigned int)u) << 16; return v.f;
}
__device__ __forceinline__ ushort_t f2bf(float f) {
    unsigned int u = __float_as_uint(f);
    unsigned int r = 0x7fffu + ((u >> 16) & 1u);
    return (ushort_t)((u + r) >> 16);
}
// shifted softplus: softplus(x) - log(2), numerically stable
__device__ __forceinline__ float sspf(float x) {
    return fmaxf(x, 0.f) + log1pf(expf(-fabsf(x))) - 0.69314718055994531f;
}

// ---------------------------------------------------------------------------
// Prep: split wf1/wf2 into bf16 hi/lo B-fragment tables (fragment-linear).
// table[(fi*64 + lane)*8 + j], fi = ks*8 + nf; element j maps to
// k = ks*32 + ((lane>>4)&3)*4 + (j&3) + 16*(j>>2), n = nf*16 + (lane&15).
// wf1f: 16 fi -> 1024 lane-slots hi + 1024 lo (elem offset 8192)
// wf2f: 32 fi -> 2048 lane-slots hi + 2048 lo (elem offset 16384)
// ---------------------------------------------------------------------------
__global__ __launch_bounds__(256) void k_prep(
    const float* __restrict__ wf1, const float* __restrict__ wf2,
    ushort_t* __restrict__ wf1f, ushort_t* __restrict__ wf2f)
{
    int s = blockIdx.x * 256 + threadIdx.x;
    if (s >= 3072) return;
    const float* W; ushort_t* out; int loOff;
    if (s < 1024) { W = wf1; out = wf1f; loOff = 8192; }
    else          { s -= 1024; W = wf2; out = wf2f; loOff = 16384; }
    const int fi = s >> 6, lane = s & 63;
    const int ks = fi >> 3, nf = fi & 7;
    const int n = nf * 16 + (lane & 15);
    const int kb = ks * 32 + ((lane >> 4) & 3) * 4;
    #pragma unroll
    for (int j = 0; j < 8; ++j) {
        const int k = kb + (j & 3) + ((j >> 2) << 4);
        const float v = W[(size_t)k * NF + n];
        const ushort_t hb = f2bf(v);
        out[(size_t)(fi * 64 + lane) * 8 + j] = hb;
        out[(size_t)loOff + (fi * 64 + lane) * 8 + j] = f2bf(v - bf2f(hb));
    }
}

// ---------------------------------------------------------------------------
// Kernel 1: y (bf16) + attention dots a_c / a_n (fp32, computed pre-rounding)
// ---------------------------------------------------------------------------
__global__ __launch_bounds__(256) void k_proj(
    const float* __restrict__ x,       // [B][N][F]
    const float* __restrict__ w_in2f,  // [H][F][F]
    const float* __restrict__ w_att,   // [H][2F]
    ushort_t* __restrict__ y,          // [B][H][N][F] bf16
    float* __restrict__ a_c,           // [B][H][N]
    float* __restrict__ a_n)           // [B][H][N]
{
    const int bn0 = blockIdx.x * 8;
    const int t = threadIdx.x;
    __shared__ float xs[8][NF];
    __shared__ float ys[32][PITCH];

    {
        const float4* src = (const float4*)(x + (size_t)bn0 * NF);
        float4* dst = (float4*)(&xs[0][0]);
        dst[t] = src[t];
    }
    __syncthreads();

    const int hp = t >> 7;
    const int f0 = t & 127;
    const int h0 = hp, h1 = hp + 2;
    const float* w0 = w_in2f + (size_t)h0 * NF * NF + f0;
    const float* w1 = w_in2f + (size_t)h1 * NF * NF + f0;
    float acc0[8], acc1[8];
    #pragma unroll
    for (int n = 0; n < 8; ++n) { acc0[n] = 0.f; acc1[n] = 0.f; }

    for (int i0 = 0; i0 < NF; i0 += 4) {
        float4 xv[8];
        #pragma unroll
        for (int n = 0; n < 8; ++n) xv[n] = *(const float4*)&xs[n][i0];
        #pragma unroll
        for (int ii = 0; ii < 4; ++ii) {
            const float wa = w0[(size_t)(i0 + ii) * NF];
            const float wb = w1[(size_t)(i0 + ii) * NF];
            #pragma unroll
            for (int n = 0; n < 8; ++n) {
                const float xi = (&xv[n].x)[ii];
                acc0[n] = fmaf(xi, wa, acc0[n]);
                acc1[n] = fmaf(xi, wb, acc1[n]);
            }
        }
    }
    #pragma unroll
    for (int n = 0; n < 8; ++n) {
        const int bn = bn0 + n;
        const int b = bn >> 10, nn = bn & (NN - 1);
        y[((size_t)(b * NH + h0) * NN + nn) * NF + f0] = f2bf(acc0[n]);
        y[((size_t)(b * NH + h1) * NN + nn) * NF + f0] = f2bf(acc1[n]);
        ys[n * 4 + h0][f0] = acc0[n];
        ys[n * 4 + h1][f0] = acc1[n];
    }
    __syncthreads();

    {
        const int hn = t >> 3, q = t & 7;
        const int h = hn & 3, n = hn >> 2;
        float pc = 0.f, pn = 0.f;
        #pragma unroll
        for (int j = 0; j < 16; ++j) {
            const int f = q + 8 * j;
            const float yv = ys[n * 4 + h][f];
            pc = fmaf(yv, w_att[h * 2 * NF + f], pc);
            pn = fmaf(yv, w_att[h * 2 * NF + NF + f], pn);
        }
        #pragma unroll
        for (int off = 1; off < 8; off <<= 1) {
            pc += __shfl_xor(pc, off, 8);
            pn += __shfl_xor(pn, off, 8);
        }
        if (q == 0) {
            const int bn = bn0 + n;
            const int b = bn >> 10, nn = bn & (NN - 1);
            a_c[(size_t)(b * NH + h) * NN + nn] = pc;
            a_n[(size_t)(b * NH + h) * NN + nn] = pn;
        }
    }
}

// ---------------------------------------------------------------------------
// Kernel 2: MFMA filter-net + attention + aggregate + out-proj, one wg/(b,n)
// W1 stored plain bf16 (error budget: round-2 measured ~3e-5 for the same
// quantization class on W2; threshold 1.135e-4). LDS 39680 B -> 4 blocks/CU.
// LDS map:
//   [0     ..16896)  W1 [64][132] ushort       --+ (both dead after A2 reads)
//   [16896 ..25600)  fijh [64][68] ushort        | -> W2f [64][132] f32 overlay
//   [25600 ..34304)  fijl [64][68] ushort      --+    at [0..33792)
//   [33792 ..37888)  aggp [8][128] f32  (written in Phase C, after overlay)
//   [37888 ..38400)  aggc [128] f32
//   [38400 ..39424)  alpha [4][64] f32
//   [39424 ..39680)  nbs [64] int
// ---------------------------------------------------------------------------
__global__ __launch_bounds__(256, 4) void k_main(
    const int*      __restrict__ neighbors, // [B][N][K]
    const float*    __restrict__ pmask,     // [B][N][K]
    const float*    __restrict__ f_ij,      // [B][N][K][G]
    const float*    __restrict__ bf1,       // [F]
    const float*    __restrict__ bf2v,      // [F]
    const float*    __restrict__ w_out,     // [F][O]
    const float*    __restrict__ b_out,     // [O]
    const ushort_t* __restrict__ y,         // [B][H][N][F] bf16
    const float*    __restrict__ a_c,       // [B][H][N]
    const float*    __restrict__ a_n,       // [B][H][N]
    const ushort_t* __restrict__ wf1f,      // frag table hi/lo
    const ushort_t* __restrict__ wf2f,      // frag table hi/lo
    float*          __restrict__ outp)      // [B][N][O]
{
    const int bn = blockIdx.x;
    const int b = bn >> 10, n_ = bn & (NN - 1);
    const int t = threadIdx.x;

    __shared__ __align__(16) char smem[39680];
    ushort_t* W1   = (ushort_t*)(smem);
    ushort_t* fijh = (ushort_t*)(smem + 16896);
    ushort_t* fijl = (ushort_t*)(smem + 25600);
    float*    W2f  = (float*)(smem);              // overlay after A2 barrier
    float*    aggp = (float*)(smem + 33792);
    float*    aggc = (float*)(smem + 37888);
    float*    alpha = (float*)(smem + 38400);
    int*      nbs   = (int*)(smem + 39424);

    const int wave = t >> 6, lane = t & 63;
    const int lrow = lane & 15;          // A-row / B-col / C-col within frag
    const int lq   = (lane >> 4) & 3;    // quarter
    const int wb   = wave * 32;          // this wave's N-column base

    // ---- stage f_ij (fp32 global, coalesced) -> bf16 hi/lo LDS ----
    {
        const float4* src = (const float4*)(f_ij + (size_t)bn * NK * NG);
        #pragma unroll
        for (int i = 0; i < 4; ++i) {
            const int e4 = i * 256 + t;
            const float4 v = src[e4];
            const int e = e4 * 4;
            const int row = e >> 6, col = e & 63;
            const ushort_t h0 = f2bf(v.x), h1 = f2bf(v.y), h2 = f2bf(v.z), h3 = f2bf(v.w);
            uint2 ph, pl;
            ph.x = (unsigned)h0 | ((unsigned)h1 << 16);
            ph.y = (unsigned)h2 | ((unsigned)h3 << 16);
            pl.x = (unsigned)f2bf(v.x - bf2f(h0)) | ((unsigned)f2bf(v.y - bf2f(h1)) << 16);
            pl.y = (unsigned)f2bf(v.z - bf2f(h2)) | ((unsigned)f2bf(v.w - bf2f(h3)) << 16);
            *(uint2*)&fijh[row * 68 + col] = ph;
            *(uint2*)&fijl[row * 68 + col] = pl;
        }
    }
    if (t < NK) nbs[t] = neighbors[(size_t)bn * NK + t];
    __syncthreads();

    // ---- Phase A1: W1 = ssp(f_ij @ wf1 + bf1), 3-term split MFMA -> bf16 ----
    {
        FragU b1h[2][2], b1l[2][2];
        #pragma unroll
        for (int ks = 0; ks < 2; ++ks)
            #pragma unroll
            for (int nf2 = 0; nf2 < 2; ++nf2) {
                const int fi = ks * 8 + wave * 2 + nf2;
                b1h[ks][nf2].u4 = *((const uint4*)wf1f + fi * 64 + lane);
                b1l[ks][nf2].u4 = *((const uint4*)(wf1f + 8192) + fi * 64 + lane);
            }
        f32x4 acc[4][2];
        #pragma unroll
        for (int mf = 0; mf < 4; ++mf)
            #pragma unroll
            for (int nf2 = 0; nf2 < 2; ++nf2) acc[mf][nf2] = (f32x4)0.f;

        #pragma unroll
        for (int mf = 0; mf < 4; ++mf) {
            const int row = mf * 16 + lrow;
            #pragma unroll
            for (int ks = 0; ks < 2; ++ks) {
                const int cb = ks * 32 + lq * 4;
                FragU ah, al;
                {
                    const uint2 p0 = *(const uint2*)&fijh[row * 68 + cb];
                    const uint2 p1 = *(const uint2*)&fijh[row * 68 + cb + 16];
                    uint4 q; q.x = p0.x; q.y = p0.y; q.z = p1.x; q.w = p1.y; ah.u4 = q;
                }
                {
                    const uint2 p0 = *(const uint2*)&fijl[row * 68 + cb];
                    const uint2 p1 = *(const uint2*)&fijl[row * 68 + cb + 16];
                    uint4 q; q.x = p0.x; q.y = p0.y; q.z = p1.x; q.w = p1.y; al.u4 = q;
                }
                #pragma unroll
                for (int nf2 = 0; nf2 < 2; ++nf2) {
                    acc[mf][nf2] = __builtin_amdgcn_mfma_f32_16x16x32_bf16(ah.s8, b1h[ks][nf2].s8, acc[mf][nf2], 0, 0, 0);
                    acc[mf][nf2] = __builtin_amdgcn_mfma_f32_16x16x32_bf16(ah.s8, b1l[ks][nf2].s8, acc[mf][nf2], 0, 0, 0);
                    acc[mf][nf2] = __builtin_amdgcn_mfma_f32_16x16x32_bf16(al.s8, b1h[ks][nf2].s8, acc[mf][nf2], 0, 0, 0);
                }
            }
        }
        const float bia[2] = { bf1[wb + lrow], bf1[wb + 16 + lrow] };
        #pragma unroll
        for (int mf = 0; mf < 4; ++mf)
            #pragma unroll
            for (int nf2 = 0; nf2 < 2; ++nf2) {
                const int col = wb + nf2 * 16 + lrow;
                #pragma unroll
                for (int r = 0; r < 4; ++r) {
                    const int row = mf * 16 + lq * 4 + r;
                    W1[row * 132 + col] = f2bf(sspf(acc[mf][nf2][r] + bia[nf2]));
                }
            }
    }
    __syncthreads();

    // ---- Phase A2: W2 = W1 @ wf2 + bf2; wf2 exact via hi+lo; W2 fp32 ----
    {
        f32x4 acc[4][2];
        #pragma unroll
        for (int mf = 0; mf < 4; ++mf)
            #pragma unroll
            for (int nf2 = 0; nf2 < 2; ++nf2) acc[mf][nf2] = (f32x4)0.f;

        for (int ks = 0; ks < 4; ++ks) {
            FragU b2h[2], b2l[2];
            #pragma unroll
            for (int nf2 = 0; nf2 < 2; ++nf2) {
                const int fi = ks * 8 + wave * 2 + nf2;
                b2h[nf2].u4 = *((const uint4*)wf2f + fi * 64 + lane);
                b2l[nf2].u4 = *((const uint4*)(wf2f + 16384) + fi * 64 + lane);
            }
            const int cb = ks * 32 + lq * 4;
            #pragma unroll
            for (int mf = 0; mf < 4; ++mf) {
                const int row = mf * 16 + lrow;
                FragU ah;
                {
                    const uint2 p0 = *(const uint2*)&W1[row * 132 + cb];
                    const uint2 p1 = *(const uint2*)&W1[row * 132 + cb + 16];
                    uint4 q; q.x = p0.x; q.y = p0.y; q.z = p1.x; q.w = p1.y; ah.u4 = q;
                }
                #pragma unroll
                for (int nf2 = 0; nf2 < 2; ++nf2) {
                    acc[mf][nf2] = __builtin_amdgcn_mfma_f32_16x16x32_bf16(ah.s8, b2h[nf2].s8, acc[mf][nf2], 0, 0, 0);
                    acc[mf][nf2] = __builtin_amdgcn_mfma_f32_16x16x32_bf16(ah.s8, b2l[nf2].s8, acc[mf][nf2], 0, 0, 0);
                }
            }
        }
        __syncthreads();   // all W1/fij reads done before W2f overlays the region
        const float bia[2] = { bf2v[wb + lrow], bf2v[wb + 16 + lrow] };
        #pragma unroll
        for (int mf = 0; mf < 4; ++mf)
            #pragma unroll
            for (int nf2 = 0; nf2 < 2; ++nf2) {
                const int col = wb + nf2 * 16 + lrow;
                #pragma unroll
                for (int r = 0; r < 4; ++r) {
                    const int row = mf * 16 + lq * 4 + r;
                    W2f[row * 132 + col] = acc[mf][nf2][r] + bia[nf2];
                }
            }
    }

    // ---- Phase B: attention softmax (wave == head), mask folded into alpha ----
    {
        const int h = wave, k = lane;
        const int nb = nbs[k];
        const float av = a_c[(size_t)(b * NH + h) * NN + n_]
                       + a_n[(size_t)(b * NH + h) * NN + nb];
        const float att = sspf(av);
        float m = att;
        #pragma unroll
        for (int off = 32; off > 0; off >>= 1) m = fmaxf(m, __shfl_xor(m, off, 64));
        const float e = expf(att - m);
        float s = e;
        #pragma unroll
        for (int off = 32; off > 0; off >>= 1) s += __shfl_xor(s, off, 64);
        alpha[h * 64 + k] = (e / s) * pmask[(size_t)bn * NK + k];
    }
    __syncthreads();   // orders W2f + alpha writes before Phase C reads

    // ---- Phase C: agg[f] = (1/H) sum_k W2[k][f] * sum_h alpha[h][k]*y[b,h,nb,f] ----
    {
        const int fq = (t & 31) * 4;
        const int kg = t >> 5;          // 0..7
        float4 accv; accv.x = accv.y = accv.z = accv.w = 0.f;
        const ushort_t* yb = y + (size_t)b * NH * NN * NF;
        #pragma unroll 2
        for (int kk = 0; kk < 8; ++kk) {
            const int k = kg * 8 + kk;
            const int nb = nbs[k];
            const ushort_t* yp = yb + (size_t)nb * NF + fq;
            const uint2 u0 = *(const uint2*)(yp);
            const uint2 u1 = *(const uint2*)(yp + (size_t)NN * NF);
            const uint2 u2 = *(const uint2*)(yp + 2 * (size_t)NN * NF);
            const uint2 u3 = *(const uint2*)(yp + 3 * (size_t)NN * NF);
            const float a0 = alpha[0 * 64 + k], a1 = alpha[1 * 64 + k];
            const float a2 = alpha[2 * 64 + k], a3 = alpha[3 * 64 + k];
            float4 s;
            s.x = fmaf(a3, bf2f((ushort_t)(u3.x & 0xffffu)),
                  fmaf(a2, bf2f((ushort_t)(u2.x & 0xffffu)),
                  fmaf(a1, bf2f((ushort_t)(u1.x & 0xffffu)),
                       a0 * bf2f((ushort_t)(u0.x & 0xffffu)))));
            s.y = fmaf(a3, bf2f((ushort_t)(u3.x >> 16)),
                  fmaf(a2, bf2f((ushort_t)(u2.x >> 16)),
                  fmaf(a1, bf2f((ushort_t)(u1.x >> 16)),
                       a0 * bf2f((ushort_t)(u0.x >> 16)))));
            s.z = fmaf(a3, bf2f((ushort_t)(u3.y & 0xffffu)),
                  fmaf(a2, bf2f((ushort_t)(u2.y & 0xffffu)),
                  fmaf(a1, bf2f((ushort_t)(u1.y & 0xffffu)),
                       a0 * bf2f((ushort_t)(u0.y & 0xffffu)))));
            s.w = fmaf(a3, bf2f((ushort_t)(u3.y >> 16)),
                  fmaf(a2, bf2f((ushort_t)(u2.y >> 16)),
                  fmaf(a1, bf2f((ushort_t)(u1.y >> 16)),
                       a0 * bf2f((ushort_t)(u0.y >> 16)))));
            const float4 wv = *(const float4*)&W2f[k * 132 + fq];
            accv.x = fmaf(wv.x, s.x, accv.x);
            accv.y = fmaf(wv.y, s.y, accv.y);
            accv.z = fmaf(wv.z, s.z, accv.z);
            accv.w = fmaf(wv.w, s.w, accv.w);
        }
        *(float4*)&aggp[kg * 128 + fq] = accv;
    }
    __syncthreads();
    if (t < NF) {
        float s = 0.f;
        #pragma unroll
        for (int q = 0; q < 8; ++q) s += aggp[q * 128 + t];
        aggc[t] = s * 0.25f;   // / H
    }
    __syncthreads();

    // ---- Phase D: out = ssp(agg @ w_out + b_out) ----
    if (t < NO) {
        float z = b_out[t];
        #pragma unroll 4
        for (int f = 0; f < NF; ++f)
            z = fmaf(aggc[f], w_out[(size_t)f * NO + t], z);
        outp[(size_t)bn * NO + t] = sspf(z);
    }
}

extern "C" void kernel_launch(void* const* d_in, const int* in_sizes, int n_in,
                              void* d_out, int out_size, void* d_ws, size_t ws_size,
                              hipStream_t stream) {
    const float* x      = (const float*)d_in[0];
    // d_in[1] = r_ij (unused by reference)
    const int*   nbr    = (const int*)d_in[2];
    const float* pmask  = (const float*)d_in[3];
    const float* f_ij   = (const float*)d_in[4];
    const float* w_in2f = (const float*)d_in[5];
    const float* w_att  = (const float*)d_in[6];
    const float* wf1    = (const float*)d_in[7];
    const float* bf1    = (const float*)d_in[8];
    const float* wf2    = (const float*)d_in[9];
    const float* bf2v   = (const float*)d_in[10];
    const float* w_out  = (const float*)d_in[11];
    const float* b_out  = (const float*)d_in[12];

    // ws layout (total 2.16 MB):
    //   yb16  [B][H][N][F] bf16 : 2 MB
    //   a_c   [B][H][N] f32     : 32 KB
    //   a_n   [B][H][N] f32     : 32 KB
    //   wf1f  hi+lo bf16 tables : 32 KB
    //   wf2f  hi+lo bf16 tables : 64 KB
    ushort_t* yb16 = (ushort_t*)d_ws;
    float*    a_c  = (float*)(yb16 + (size_t)NB * NH * NN * NF);
    float*    a_n  = a_c + (size_t)NB * NH * NN;
    ushort_t* wf1f = (ushort_t*)(a_n + (size_t)NB * NH * NN);
    ushort_t* wf2f = wf1f + 16384;

    float* outp = (float*)d_out;

    k_prep<<<12, 256, 0, stream>>>(wf1, wf2, wf1f, wf2f);
    k_proj<<<NB * NN / 8, 256, 0, stream>>>(x, w_in2f, w_att, yb16, a_c, a_n);
    k_main<<<NB * NN, 256, 0, stream>>>(nbr, pmask, f_ij, bf1, bf2v,
                                        w_out, b_out, yb16, a_c, a_n, wf1f, wf2f, outp);
}

// Round 8
// 64.239 us; speedup vs baseline: 2.6344x; 1.4288x over previous
//
#include <hip/hip_runtime.h>

#define NB 2
#define NN 1024
#define NK 64
#define NG 64
#define NF 128
#define NH 4
#define NO 128
#define PITCH 132   // ys pitch in k_proj (bank-spread)

typedef unsigned short ushort_t;
typedef __attribute__((ext_vector_type(8))) short short8v;
typedef __attribute__((ext_vector_type(4))) float f32x4;

union FragU { uint4 u4; short8v s8; };

__device__ __forceinline__ float bf2f(ushort_t u) {
    union { unsigned int i; float f; } v; v.i = ((unsigned int)u) << 16; return v.f;
}
__device__ __forceinline__ ushort_t f2bf(float f) {
    unsigned int u = __float_as_uint(f);
    unsigned int r = 0x7fffu + ((u >> 16) & 1u);
    return (ushort_t)((u + r) >> 16);
}
// shifted softplus via hardware exp2/log2 (v_exp_f32 / v_log_f32 through the
// amdgcn builtins; __exp2f/__log2f don't exist in HIP and collide with glibc):
// ssp(x) = max(x,0) + ln2*log2(1 + 2^(-|x|*log2e)) - ln2; abs err ~1e-7.
__device__ __forceinline__ float sspf(float x) {
    const float u = __builtin_amdgcn_exp2f(-fabsf(x) * 1.44269504088896341f);
    return fmaxf(x, 0.f) + fmaf(0.69314718055994531f,
                                __builtin_amdgcn_logf(1.f + u),
                                -0.69314718055994531f);
}

// ---------------------------------------------------------------------------
// Prep: split wf1/wf2 into bf16 hi/lo B-fragment tables (fragment-linear),
// plus transpose w_out -> w_outT[o][f] for vectorized Phase D loads.
// table[(fi*64 + lane)*8 + j], fi = ks*8 + nf; element j maps to
// k = ks*32 + ((lane>>4)&3)*4 + (j&3) + 16*(j>>2), n = nf*16 + (lane&15).
// wf1f: 16 fi -> 1024 lane-slots hi + 1024 lo (elem offset 8192)
// wf2f: 32 fi -> 2048 lane-slots hi + 2048 lo (elem offset 16384)
// slots [3072..7168): w_outT transpose, 4 elements per slot.
// ---------------------------------------------------------------------------
__global__ __launch_bounds__(256) void k_prep(
    const float* __restrict__ wf1, const float* __restrict__ wf2,
    const float* __restrict__ w_out,
    ushort_t* __restrict__ wf1f, ushort_t* __restrict__ wf2f,
    float* __restrict__ w_outT)
{
    int s = blockIdx.x * 256 + threadIdx.x;
    if (s >= 7168) return;
    if (s >= 3072) {
        const int s2 = s - 3072;           // [0,4096)
        const int o = s2 >> 5, fb = s2 & 31;
        #pragma unroll
        for (int j = 0; j < 4; ++j)
            w_outT[(size_t)o * NF + fb * 4 + j] = w_out[(size_t)(fb * 4 + j) * NO + o];
        return;
    }
    const float* W; ushort_t* out; int loOff;
    if (s < 1024) { W = wf1; out = wf1f; loOff = 8192; }
    else          { s -= 1024; W = wf2; out = wf2f; loOff = 16384; }
    const int fi = s >> 6, lane = s & 63;
    const int ks = fi >> 3, nf = fi & 7;
    const int n = nf * 16 + (lane & 15);
    const int kb = ks * 32 + ((lane >> 4) & 3) * 4;
    #pragma unroll
    for (int j = 0; j < 8; ++j) {
        const int k = kb + (j & 3) + ((j >> 2) << 4);
        const float v = W[(size_t)k * NF + n];
        const ushort_t hb = f2bf(v);
        out[(size_t)(fi * 64 + lane) * 8 + j] = hb;
        out[(size_t)loOff + (fi * 64 + lane) * 8 + j] = f2bf(v - bf2f(hb));
    }
}

// ---------------------------------------------------------------------------
// Kernel 1: y (bf16) + attention dots a_c / a_n (fp32, computed pre-rounding)
// ---------------------------------------------------------------------------
__global__ __launch_bounds__(256) void k_proj(
    const float* __restrict__ x,       // [B][N][F]
    const float* __restrict__ w_in2f,  // [H][F][F]
    const float* __restrict__ w_att,   // [H][2F]
    ushort_t* __restrict__ y,          // [B][H][N][F] bf16
    float* __restrict__ a_c,           // [B][H][N]
    float* __restrict__ a_n)           // [B][H][N]
{
    const int bn0 = blockIdx.x * 8;
    const int t = threadIdx.x;
    __shared__ float xs[8][NF];
    __shared__ float ys[32][PITCH];

    {
        const float4* src = (const float4*)(x + (size_t)bn0 * NF);
        float4* dst = (float4*)(&xs[0][0]);
        dst[t] = src[t];
    }
    __syncthreads();

    const int hp = t >> 7;
    const int f0 = t & 127;
    const int h0 = hp, h1 = hp + 2;
    const float* w0 = w_in2f + (size_t)h0 * NF * NF + f0;
    const float* w1 = w_in2f + (size_t)h1 * NF * NF + f0;
    float acc0[8], acc1[8];
    #pragma unroll
    for (int n = 0; n < 8; ++n) { acc0[n] = 0.f; acc1[n] = 0.f; }

    for (int i0 = 0; i0 < NF; i0 += 4) {
        float4 xv[8];
        #pragma unroll
        for (int n = 0; n < 8; ++n) xv[n] = *(const float4*)&xs[n][i0];
        #pragma unroll
        for (int ii = 0; ii < 4; ++ii) {
            const float wa = w0[(size_t)(i0 + ii) * NF];
            const float wb = w1[(size_t)(i0 + ii) * NF];
            #pragma unroll
            for (int n = 0; n < 8; ++n) {
                const float xi = (&xv[n].x)[ii];
                acc0[n] = fmaf(xi, wa, acc0[n]);
                acc1[n] = fmaf(xi, wb, acc1[n]);
            }
        }
    }
    #pragma unroll
    for (int n = 0; n < 8; ++n) {
        const int bn = bn0 + n;
        const int b = bn >> 10, nn = bn & (NN - 1);
        y[((size_t)(b * NH + h0) * NN + nn) * NF + f0] = f2bf(acc0[n]);
        y[((size_t)(b * NH + h1) * NN + nn) * NF + f0] = f2bf(acc1[n]);
        ys[n * 4 + h0][f0] = acc0[n];
        ys[n * 4 + h1][f0] = acc1[n];
    }
    __syncthreads();

    {
        const int hn = t >> 3, q = t & 7;
        const int h = hn & 3, n = hn >> 2;
        float pc = 0.f, pn = 0.f;
        #pragma unroll
        for (int j = 0; j < 16; ++j) {
            const int f = q + 8 * j;
            const float yv = ys[n * 4 + h][f];
            pc = fmaf(yv, w_att[h * 2 * NF + f], pc);
            pn = fmaf(yv, w_att[h * 2 * NF + NF + f], pn);
        }
        #pragma unroll
        for (int off = 1; off < 8; off <<= 1) {
            pc += __shfl_xor(pc, off, 8);
            pn += __shfl_xor(pn, off, 8);
        }
        if (q == 0) {
            const int bn = bn0 + n;
            const int b = bn >> 10, nn = bn & (NN - 1);
            a_c[(size_t)(b * NH + h) * NN + nn] = pc;
            a_n[(size_t)(b * NH + h) * NN + nn] = pn;
        }
    }
}

// ---------------------------------------------------------------------------
// Kernel 2: MFMA filter-net + attention + aggregate + out-proj, one wg/(b,n)
// LDS 39680 B -> 4 blocks/CU.
// LDS map:
//   [0     ..16896)  W1 [64][132] ushort       --+ (both dead after A2 reads)
//   [16896 ..25600)  fijh [64][68] ushort        | -> W2f [64][132] f32 overlay
//   [25600 ..34304)  fijl [64][68] ushort      --+    at [0..33792)
//   [33792 ..37888)  aggp [8][128] f32  (written in Phase C, after overlay)
//   [37888 ..38400)  aggc [128] f32
//   [38400 ..39424)  alpha [4][64] f32
//   [39424 ..39680)  nbs [64] int
// ---------------------------------------------------------------------------
__global__ __launch_bounds__(256, 4) void k_main(
    const int*      __restrict__ neighbors, // [B][N][K]
    const float*    __restrict__ pmask,     // [B][N][K]
    const float*    __restrict__ f_ij,      // [B][N][K][G]
    const float*    __restrict__ bf1,       // [F]
    const float*    __restrict__ bf2v,      // [F]
    const float*    __restrict__ w_outT,    // [O][F] transposed
    const float*    __restrict__ b_out,     // [O]
    const ushort_t* __restrict__ y,         // [B][H][N][F] bf16
    const float*    __restrict__ a_c,       // [B][H][N]
    const float*    __restrict__ a_n,       // [B][H][N]
    const ushort_t* __restrict__ wf1f,      // frag table hi/lo
    const ushort_t* __restrict__ wf2f,      // frag table hi/lo
    float*          __restrict__ outp)      // [B][N][O]
{
    const int bn = blockIdx.x;
    const int b = bn >> 10, n_ = bn & (NN - 1);
    const int t = threadIdx.x;

    __shared__ __align__(16) char smem[39680];
    ushort_t* W1   = (ushort_t*)(smem);
    ushort_t* fijh = (ushort_t*)(smem + 16896);
    ushort_t* fijl = (ushort_t*)(smem + 25600);
    float*    W2f  = (float*)(smem);              // overlay after A2 barrier
    float*    aggp = (float*)(smem + 33792);
    float*    aggc = (float*)(smem + 37888);
    float*    alpha = (float*)(smem + 38400);
    int*      nbs   = (int*)(smem + 39424);

    const int wave = t >> 6, lane = t & 63;
    const int lrow = lane & 15;          // A-row / B-col / C-col within frag
    const int lq   = (lane >> 4) & 3;    // quarter
    const int wb   = wave * 32;          // this wave's N-column base

    // ---- stage f_ij (fp32 global, coalesced) -> bf16 hi/lo LDS ----
    {
        const float4* src = (const float4*)(f_ij + (size_t)bn * NK * NG);
        #pragma unroll
        for (int i = 0; i < 4; ++i) {
            const int e4 = i * 256 + t;
            const float4 v = src[e4];
            const int e = e4 * 4;
            const int row = e >> 6, col = e & 63;
            const ushort_t h0 = f2bf(v.x), h1 = f2bf(v.y), h2 = f2bf(v.z), h3 = f2bf(v.w);
            uint2 ph, pl;
            ph.x = (unsigned)h0 | ((unsigned)h1 << 16);
            ph.y = (unsigned)h2 | ((unsigned)h3 << 16);
            pl.x = (unsigned)f2bf(v.x - bf2f(h0)) | ((unsigned)f2bf(v.y - bf2f(h1)) << 16);
            pl.y = (unsigned)f2bf(v.z - bf2f(h2)) | ((unsigned)f2bf(v.w - bf2f(h3)) << 16);
            *(uint2*)&fijh[row * 68 + col] = ph;
            *(uint2*)&fijl[row * 68 + col] = pl;
        }
    }
    if (t < NK) nbs[t] = neighbors[(size_t)bn * NK + t];
    __syncthreads();

    // ---- Phase A1: W1 = ssp(f_ij @ wf1 + bf1), 3-term split MFMA -> bf16 ----
    {
        FragU b1h[2][2], b1l[2][2];
        #pragma unroll
        for (int ks = 0; ks < 2; ++ks)
            #pragma unroll
            for (int nf2 = 0; nf2 < 2; ++nf2) {
                const int fi = ks * 8 + wave * 2 + nf2;
                b1h[ks][nf2].u4 = *((const uint4*)wf1f + fi * 64 + lane);
                b1l[ks][nf2].u4 = *((const uint4*)(wf1f + 8192) + fi * 64 + lane);
            }
        f32x4 acc[4][2];
        #pragma unroll
        for (int mf = 0; mf < 4; ++mf)
            #pragma unroll
            for (int nf2 = 0; nf2 < 2; ++nf2) acc[mf][nf2] = (f32x4)0.f;

        #pragma unroll
        for (int mf = 0; mf < 4; ++mf) {
            const int row = mf * 16 + lrow;
            #pragma unroll
            for (int ks = 0; ks < 2; ++ks) {
                const int cb = ks * 32 + lq * 4;
                FragU ah, al;
                {
                    const uint2 p0 = *(const uint2*)&fijh[row * 68 + cb];
                    const uint2 p1 = *(const uint2*)&fijh[row * 68 + cb + 16];
                    uint4 q; q.x = p0.x; q.y = p0.y; q.z = p1.x; q.w = p1.y; ah.u4 = q;
                }
                {
                    const uint2 p0 = *(const uint2*)&fijl[row * 68 + cb];
                    const uint2 p1 = *(const uint2*)&fijl[row * 68 + cb + 16];
                    uint4 q; q.x = p0.x; q.y = p0.y; q.z = p1.x; q.w = p1.y; al.u4 = q;
                }
                #pragma unroll
                for (int nf2 = 0; nf2 < 2; ++nf2) {
                    acc[mf][nf2] = __builtin_amdgcn_mfma_f32_16x16x32_bf16(ah.s8, b1h[ks][nf2].s8, acc[mf][nf2], 0, 0, 0);
                    acc[mf][nf2] = __builtin_amdgcn_mfma_f32_16x16x32_bf16(ah.s8, b1l[ks][nf2].s8, acc[mf][nf2], 0, 0, 0);
                    acc[mf][nf2] = __builtin_amdgcn_mfma_f32_16x16x32_bf16(al.s8, b1h[ks][nf2].s8, acc[mf][nf2], 0, 0, 0);
                }
            }
        }
        const float bia[2] = { bf1[wb + lrow], bf1[wb + 16 + lrow] };
        #pragma unroll
        for (int mf = 0; mf < 4; ++mf)
            #pragma unroll
            for (int nf2 = 0; nf2 < 2; ++nf2) {
                const int col = wb + nf2 * 16 + lrow;
                #pragma unroll
                for (int r = 0; r < 4; ++r) {
                    const int row = mf * 16 + lq * 4 + r;
                    W1[row * 132 + col] = f2bf(sspf(acc[mf][nf2][r] + bia[nf2]));
                }
            }
    }
    __syncthreads();

    // ---- Phase A2: W2 = W1 @ wf2 + bf2; wf2 exact via hi+lo; W2 fp32 ----
    {
        f32x4 acc[4][2];
        #pragma unroll
        for (int mf = 0; mf < 4; ++mf)
            #pragma unroll
            for (int nf2 = 0; nf2 < 2; ++nf2) acc[mf][nf2] = (f32x4)0.f;

        for (int ks = 0; ks < 4; ++ks) {
            FragU b2h[2], b2l[2];
            #pragma unroll
            for (int nf2 = 0; nf2 < 2; ++nf2) {
                const int fi = ks * 8 + wave * 2 + nf2;
                b2h[nf2].u4 = *((const uint4*)wf2f + fi * 64 + lane);
                b2l[nf2].u4 = *((const uint4*)(wf2f + 16384) + fi * 64 + lane);
            }
            const int cb = ks * 32 + lq * 4;
            #pragma unroll
            for (int mf = 0; mf < 4; ++mf) {
                const int row = mf * 16 + lrow;
                FragU ah;
                {
                    const uint2 p0 = *(const uint2*)&W1[row * 132 + cb];
                    const uint2 p1 = *(const uint2*)&W1[row * 132 + cb + 16];
                    uint4 q; q.x = p0.x; q.y = p0.y; q.z = p1.x; q.w = p1.y; ah.u4 = q;
                }
                #pragma unroll
                for (int nf2 = 0; nf2 < 2; ++nf2) {
                    acc[mf][nf2] = __builtin_amdgcn_mfma_f32_16x16x32_bf16(ah.s8, b2h[nf2].s8, acc[mf][nf2], 0, 0, 0);
                    acc[mf][nf2] = __builtin_amdgcn_mfma_f32_16x16x32_bf16(ah.s8, b2l[nf2].s8, acc[mf][nf2], 0, 0, 0);
                }
            }
        }
        __syncthreads();   // all W1/fij reads done before W2f overlays the region
        const float bia[2] = { bf2v[wb + lrow], bf2v[wb + 16 + lrow] };
        #pragma unroll
        for (int mf = 0; mf < 4; ++mf)
            #pragma unroll
            for (int nf2 = 0; nf2 < 2; ++nf2) {
                const int col = wb + nf2 * 16 + lrow;
                #pragma unroll
                for (int r = 0; r < 4; ++r) {
                    const int row = mf * 16 + lq * 4 + r;
                    W2f[row * 132 + col] = acc[mf][nf2][r] + bia[nf2];
                }
            }
    }

    // ---- Phase B: attention softmax (wave == head), mask folded into alpha ----
    {
        const int h = wave, k = lane;
        const int nb = nbs[k];
        const float av = a_c[(size_t)(b * NH + h) * NN + n_]
                       + a_n[(size_t)(b * NH + h) * NN + nb];
        const float att = sspf(av);
        float m = att;
        #pragma unroll
        for (int off = 32; off > 0; off >>= 1) m = fmaxf(m, __shfl_xor(m, off, 64));
        const float e = __builtin_amdgcn_exp2f((att - m) * 1.44269504088896341f);
        float s = e;
        #pragma unroll
        for (int off = 32; off > 0; off >>= 1) s += __shfl_xor(s, off, 64);
        alpha[h * 64 + k] = (e / s) * pmask[(size_t)bn * NK + k];
    }
    __syncthreads();   // orders W2f + alpha writes before Phase C reads

    // ---- Phase C: agg[f] = (1/H) sum_k W2[k][f] * sum_h alpha[h][k]*y[b,h,nb,f] ----
    {
        const int fq = (t & 31) * 4;
        const int kg = t >> 5;          // 0..7
        float4 accv; accv.x = accv.y = accv.z = accv.w = 0.f;
        const ushort_t* yb = y + (size_t)b * NH * NN * NF;
        #pragma unroll 4
        for (int kk = 0; kk < 8; ++kk) {
            const int k = kg * 8 + kk;
            const int nb = nbs[k];
            const ushort_t* yp = yb + (size_t)nb * NF + fq;
            const uint2 u0 = *(const uint2*)(yp);
            const uint2 u1 = *(const uint2*)(yp + (size_t)NN * NF);
            const uint2 u2 = *(const uint2*)(yp + 2 * (size_t)NN * NF);
            const uint2 u3 = *(const uint2*)(yp + 3 * (size_t)NN * NF);
            const float a0 = alpha[0 * 64 + k], a1 = alpha[1 * 64 + k];
            const float a2 = alpha[2 * 64 + k], a3 = alpha[3 * 64 + k];
            float4 s;
            s.x = fmaf(a3, bf2f((ushort_t)(u3.x & 0xffffu)),
                  fmaf(a2, bf2f((ushort_t)(u2.x & 0xffffu)),
                  fmaf(a1, bf2f((ushort_t)(u1.x & 0xffffu)),
                       a0 * bf2f((ushort_t)(u0.x & 0xffffu)))));
            s.y = fmaf(a3, bf2f((ushort_t)(u3.x >> 16)),
                  fmaf(a2, bf2f((ushort_t)(u2.x >> 16)),
                  fmaf(a1, bf2f((ushort_t)(u1.x >> 16)),
                       a0 * bf2f((ushort_t)(u0.x >> 16)))));
            s.z = fmaf(a3, bf2f((ushort_t)(u3.y & 0xffffu)),
                  fmaf(a2, bf2f((ushort_t)(u2.y & 0xffffu)),
                  fmaf(a1, bf2f((ushort_t)(u1.y & 0xffffu)),
                       a0 * bf2f((ushort_t)(u0.y & 0xffffu)))));
            s.w = fmaf(a3, bf2f((ushort_t)(u3.y >> 16)),
                  fmaf(a2, bf2f((ushort_t)(u2.y >> 16)),
                  fmaf(a1, bf2f((ushort_t)(u1.y >> 16)),
                       a0 * bf2f((ushort_t)(u0.y >> 16)))));
            const float4 wv = *(const float4*)&W2f[k * 132 + fq];
            accv.x = fmaf(wv.x, s.x, accv.x);
            accv.y = fmaf(wv.y, s.y, accv.y);
            accv.z = fmaf(wv.z, s.z, accv.z);
            accv.w = fmaf(wv.w, s.w, accv.w);
        }
        *(float4*)&aggp[kg * 128 + fq] = accv;
    }
    __syncthreads();
    if (t < NF) {
        float s = 0.f;
        #pragma unroll
        for (int q = 0; q < 8; ++q) s += aggp[q * 128 + t];
        aggc[t] = s * 0.25f;   // / H
    }
    __syncthreads();

    // ---- Phase D: out = ssp(agg @ w_outT + b_out), vectorized loads ----
    if (t < NO) {
        float z = b_out[t];
        const float4* wr = (const float4*)(w_outT + (size_t)t * NF);
        #pragma unroll 8
        for (int q = 0; q < NF / 4; ++q) {
            const float4 w = wr[q];
            const float4 a = *(const float4*)&aggc[q * 4];
            z = fmaf(a.x, w.x, fmaf(a.y, w.y, fmaf(a.z, w.z, fmaf(a.w, w.w, z))));
        }
        outp[(size_t)bn * NO + t] = sspf(z);
    }
}

extern "C" void kernel_launch(void* const* d_in, const int* in_sizes, int n_in,
                              void* d_out, int out_size, void* d_ws, size_t ws_size,
                              hipStream_t stream) {
    const float* x      = (const float*)d_in[0];
    // d_in[1] = r_ij (unused by reference)
    const int*   nbr    = (const int*)d_in[2];
    const float* pmask  = (const float*)d_in[3];
    const float* f_ij   = (const float*)d_in[4];
    const float* w_in2f = (const float*)d_in[5];
    const float* w_att  = (const float*)d_in[6];
    const float* wf1    = (const float*)d_in[7];
    const float* bf1    = (const float*)d_in[8];
    const float* wf2    = (const float*)d_in[9];
    const float* bf2v   = (const float*)d_in[10];
    const float* w_out  = (const float*)d_in[11];
    const float* b_out  = (const float*)d_in[12];

    // ws layout (total ~2.22 MB):
    //   yb16  [B][H][N][F] bf16 : 2 MB
    //   a_c   [B][H][N] f32     : 32 KB
    //   a_n   [B][H][N] f32     : 32 KB
    //   wf1f  hi+lo bf16 tables : 32 KB
    //   wf2f  hi+lo bf16 tables : 64 KB
    //   w_outT [O][F] f32       : 64 KB
    ushort_t* yb16  = (ushort_t*)d_ws;
    float*    a_c   = (float*)(yb16 + (size_t)NB * NH * NN * NF);
    float*    a_n   = a_c + (size_t)NB * NH * NN;
    ushort_t* wf1f  = (ushort_t*)(a_n + (size_t)NB * NH * NN);
    ushort_t* wf2f  = wf1f + 16384;
    float*    w_outT = (float*)(wf2f + 32768);

    float* outp = (float*)d_out;

    k_prep<<<28, 256, 0, stream>>>(wf1, wf2, w_out, wf1f, wf2f, w_outT);
    k_proj<<<NB * NN / 8, 256, 0, stream>>>(x, w_in2f, w_att, yb16, a_c, a_n);
    k_main<<<NB * NN, 256, 0, stream>>>(nbr, pmask, f_ij, bf1, bf2v,
                                        w_outT, b_out, yb16, a_c, a_n, wf1f, wf2f, outp);
}